// Round 16
// baseline (90.570 us; speedup 1.0000x reference)
//
#include <hip/hip_runtime.h>
#include <cstddef>

#define SEQLEN 32
#define BATCH  32768
#define POSE   34
#define PREDL  15
#define LOG2E  1.4426950408889634f
#define K2E    2.8853901817779268f

typedef __attribute__((ext_vector_type(8))) short short8;
typedef __attribute__((ext_vector_type(4))) float f32x4;
typedef union { short8 s8; unsigned u[4]; } pk8;

#define MF(a,b,c) __builtin_amdgcn_mfma_f32_16x16x32_bf16(a,b,c,0,0,0)
#define EXP2(x)  __builtin_amdgcn_exp2f(x)
#define RCP(x)   __builtin_amdgcn_rcpf(x)

__device__ __forceinline__ unsigned short f2bf(float f){ __bf16 b=(__bf16)f; return __builtin_bit_cast(unsigned short,b); }
__device__ __forceinline__ unsigned f22bf(float lo,float hi){ return (unsigned)f2bf(lo) | ((unsigned)f2bf(hi)<<16); }
__device__ __forceinline__ short8 zero8(){ pk8 r; r.u[0]=0;r.u[1]=0;r.u[2]=0;r.u[3]=0; return r.s8; }
__device__ __forceinline__ float scGT(int gt){ return (gt==2)?K2E:LOG2E; }

__device__ __forceinline__ short8 g8s(const float* __restrict__ p, float s){
    pk8 r;
    r.u[0]=f22bf(p[0]*s,p[1]*s); r.u[1]=f22bf(p[2]*s,p[3]*s);
    r.u[2]=f22bf(p[4]*s,p[5]*s); r.u[3]=f22bf(p[6]*s,p[7]*s);
    return r.s8;
}

// ---- FMA-only transcendentals (no trans-pipe ops) ----
// exp2: range-reduce to f in [-0.5,0.5], deg-4 Taylor (err ~4e-5), ldexp via int add.
__device__ __forceinline__ float exp2sw(float x){
    x = fminf(fmaxf(x, -60.f), 60.f);
    float j = __builtin_rintf(x);
    float f = x - j;
    float p = fmaf(f, fmaf(f, fmaf(f, fmaf(f, 0.0096181291f, 0.0555041087f),
                                   0.2402265069f), 0.6931471806f), 1.0f);
    int e = (int)j;
    return __builtin_bit_cast(float, __builtin_bit_cast(int, p) + (e << 23));
}
// rcp for strictly-positive normal x: magic guess + 2 Newton (rel err ~1e-4)
__device__ __forceinline__ float rcpsw(float x){
    float y = __builtin_bit_cast(float, 0x7EF127EAu - __builtin_bit_cast(unsigned, x));
    y = y * (2.0f - x * y);
    y = y * (2.0f - x * y);
    return y;
}

// packed trans-reduced pointwise — same algebra as R10, all math on the full-rate pipe
__device__ __forceinline__ void pw4v(const f32x4 (&ac)[4], f32x4 &cs,
                                     unsigned &hp0, unsigned &hp1){
    f32x4 A,C,B,O;
#pragma unroll
    for(int j=0;j<4;++j){
        A[j]=exp2sw(-ac[0][j]); C[j]=exp2sw(-ac[1][j]);
        B[j]=exp2sw( ac[2][j]); O[j]=exp2sw(-ac[3][j]);
    }
    const f32x4 one={1.f,1.f,1.f,1.f};
    f32x4 u=one+A, w=one+C, v=B+one, Bm=B-one;
    f32x4 t1=u*v;
    f32x4 num=cs*t1+Bm*w;
    f32x4 den=t1*w;
    f32x4 rd_,E,rh;
#pragma unroll
    for(int j=0;j<4;++j) rd_[j]=rcpsw(den[j]);
    f32x4 cn=num*rd_;
    cs=cn;
#pragma unroll
    for(int j=0;j<4;++j) E[j]=exp2sw(K2E*cn[j]);
    f32x4 hd=(one+O)*(E+one);
#pragma unroll
    for(int j=0;j<4;++j) rh[j]=rcpsw(hd[j]);
    f32x4 hv=(E-one)*rh;
    hp0=f22bf(hv[0],hv[1]); hp1=f22bf(hv[2],hv[3]);
}

// ---- prep: fold decoder/crossing weights, pre-scaled, into workspace ----
extern "C" __global__ void lstm_prep(
    const float* __restrict__ dWih, const float* __restrict__ dWhh,
    const float* __restrict__ dbih, const float* __restrict__ dbhh,
    const float* __restrict__ cWih, const float* __restrict__ cWhh,
    const float* __restrict__ cbih, const float* __restrict__ cbhh,
    const float* __restrict__ fcW,  const float* __restrict__ fcb,
    const float* __restrict__ embW, const float* __restrict__ embb,
    float* __restrict__ wsBD, float* __restrict__ wsBC,
    unsigned short* __restrict__ wsDh, unsigned short* __restrict__ wsCh,
    unsigned short* __restrict__ wsCp)
{
    int idx = blockIdx.x*256 + threadIdx.x;
    if(idx < 1024){
        int R=idx>>4, k=idx&15;
        float s=scGT(R>>4);
        float vD=dWhh[R*16+k];
        for(int p=0;p<34;++p) vD=fmaf(dWih[R*34+p],fcW[p*16+k],vD);
        wsDh[idx]=f2bf(vD*s);
        wsCh[idx]=f2bf(cWhh[R*16+k]*s);
    }
    if(idx < 128){
        int R=idx>>1, k=idx&1;
        float s=scGT(R>>4);
        float v=0.f;
        for(int p=0;p<34;++p) v=fmaf(cWih[R*34+p],embW[2*p+k],v);
        wsCp[idx]=f2bf(v*s);
    }
    if(idx < 64){
        int R=idx;
        float s=scGT(R>>4);
        float vD=dbih[R]+dbhh[R], vC=cbih[R]+cbhh[R];
        for(int p=0;p<34;++p){ vD=fmaf(dWih[R*34+p],fcb[p],vD); vC=fmaf(cWih[R*34+p],embb[p],vC); }
        wsBD[idx]=vD*s; wsBC[idx]=vC*s;
    }
}

extern "C" __global__ void __launch_bounds__(256,2) lstm_w9(
    const float* __restrict__ obs_s,
    const float* __restrict__ eWih, const float* __restrict__ eWhh,
    const float* __restrict__ ebih, const float* __restrict__ ebhh,
    const float* __restrict__ dWih, const float* __restrict__ dWhh,
    const float* __restrict__ dbih, const float* __restrict__ dbhh,
    const float* __restrict__ cWih, const float* __restrict__ cWhh,
    const float* __restrict__ cbih, const float* __restrict__ cbhh,
    const float* __restrict__ fcW,  const float* __restrict__ fcb,
    const float* __restrict__ fccW, const float* __restrict__ fccb,
    const float* __restrict__ mlpW, const float* __restrict__ mlpb,
    const float* __restrict__ wsBD, const float* __restrict__ wsBC,
    const unsigned short* __restrict__ wsDh, const unsigned short* __restrict__ wsCh,
    const unsigned short* __restrict__ wsCp,
    float* __restrict__ out_s, float* __restrict__ out_cr)
{
    __shared__ unsigned xt4[4][4][320];   // per-wave: 4 step-slots x (16 rows x 20 words)

    const int tid=threadIdx.x;
    const int l=tid&63;
    const int wv=tid>>6;
    const int lo=l&15, g=l>>4;
    const int pb=blockIdx.x*64 + wv*16;
    unsigned* XT=&xt4[wv][0][0];

    unsigned pofs[5]; int wofs[5];
#pragma unroll
    for(int it=0; it<5; ++it){
        int i2=l+64*it;
        int r=i2/17, w=i2-r*17;
        pofs[it]=(unsigned)((pb+r)*17+w);
        wofs[it]=r*20+w;
    }

    // ---- encoder weights: A-frags, pre-scaled; bias as C-frag ----
    short8 wEx[4], wEhT[4]; f32x4 biasE[4];
#pragma unroll
    for(int gt=0;gt<4;++gt){
        float s=scGT(gt);
        int R=gt*16+lo;
        wEx[gt]=g8s(&eWih[R*34+8*g], s);
        pk8 r2;
        r2.u[0]=f22bf(eWhh[R*16+4*g]*s,   eWhh[R*16+4*g+1]*s);
        r2.u[1]=f22bf(eWhh[R*16+4*g+2]*s, eWhh[R*16+4*g+3]*s);
        r2.u[2]=(g==0)? f22bf(eWih[R*34+32]*s, eWih[R*34+33]*s) : 0u;
        r2.u[3]=0u;
        wEhT[gt]=r2.s8;
        float4 ba=*(const float4*)&ebih[gt*16+4*g];
        float4 bb=*(const float4*)&ebhh[gt*16+4*g];
        biasE[gt]=f32x4{(ba.x+bb.x)*s,(ba.y+bb.y)*s,(ba.z+bb.z)*s,(ba.w+bb.w)*s};
    }

    f32x4 cS={0.f,0.f,0.f,0.f};
    unsigned hp0=0u, hp1=0u;

    float2 RA[4][5];
    auto ldblk=[&](float2 (&R)[4][5], int t0){
#pragma unroll
        for(int s=0;s<4;++s){
            const float2* base=(const float2*)obs_s + (size_t)(t0+s)*(BATCH*17);
#pragma unroll
            for(int it=0;it<5;++it)
                if(it<4 || l<16) R[s][it]=base[pofs[it]];
        }
    };
    auto wrblk=[&](const float2 (&R)[4][5]){
#pragma unroll
        for(int s=0;s<4;++s)
#pragma unroll
            for(int it=0;it<5;++it)
                if(it<4 || l<16) XT[s*320+wofs[it]]=f22bf(R[s][it].x,R[s][it].y);
    };

    // ---- encoder: 8 blocks of 4 steps; x-MFMAs hoisted off the chain ----
    short8 fbQ=zero8(); unsigned ftQ=0u;
    ldblk(RA,0);
#pragma unroll
    for(int kb=0;kb<8;++kb){
        wrblk(RA);
        if(kb+1<8) ldblk(RA,4*(kb+1));        // refill for next block (WAR, in-order)
        short8 bx[4]; unsigned tw[4];
#pragma unroll
        for(int s=0;s<4;++s){
            bx[s]=*(const short8*)&XT[s*320+lo*20+4*g];
            tw[s]=XT[s*320+lo*20+16];
        }
        f32x4 cx[4][4];
#pragma unroll
        for(int s=0;s<4;++s)
#pragma unroll
            for(int gt=0;gt<4;++gt)
                cx[s][gt]=MF(wEx[gt],bx[s],biasE[gt]);   // off-chain x-part + bias
        if(kb==7){ fbQ=bx[3]; ftQ=tw[3]; }
#pragma unroll
        for(int s=0;s<4;++s){                            // pure-register chain loop
            pk8 bh; bh.u[0]=hp0; bh.u[1]=hp1; bh.u[2]=(g==0)?tw[s]:0u; bh.u[3]=0u;
            f32x4 acc[4];
#pragma unroll
            for(int gt=0;gt<4;++gt) acc[gt]=MF(wEhT[gt],bh.s8,cx[s][gt]);
            pw4v(acc,cS,hp0,hp1);
        }
    }

    // ---- decoder weights -> VGPRs (folded, pre-scaled) ----
    short8 wDh[4], wCA[4]; f32x4 biasD[4], biasC[4];
#pragma unroll
    for(int gt=0;gt<4;++gt){
        int R=gt*16+lo;
        uint2 qd=*(const uint2*)&wsDh[R*16+4*g];
        pk8 rd; rd.u[0]=qd.x; rd.u[1]=qd.y; rd.u[2]=0u; rd.u[3]=0u;
        wDh[gt]=rd.s8;
        uint2 qc=*(const uint2*)&wsCh[R*16+4*g];
        pk8 rc; rc.u[0]=qc.x; rc.u[1]=qc.y;
        rc.u[2]=(g==0)? *(const unsigned*)&wsCp[R*2] : 0u; rc.u[3]=0u;
        wCA[gt]=rc.s8;
        biasD[gt]=*(const f32x4*)&wsBD[gt*16+4*g];
        biasC[gt]=*(const f32x4*)&wsBC[gt*16+4*g];
    }
    short8 wF[3]; f32x4 fcbF[3];
#pragma unroll
    for(int nt=0;nt<3;++nt){
        int np=nt*16+lo;
        if(np<POSE){
            pk8 r;
            r.u[0]=f22bf(fcW[np*16+4*g],   fcW[np*16+4*g+1]);
            r.u[1]=f22bf(fcW[np*16+4*g+2], fcW[np*16+4*g+3]);
            r.u[2]=0u; r.u[3]=0u;
            wF[nt]=r.s8;
        } else wF[nt]=zero8();
#pragma unroll
        for(int j=0;j<4;++j){
            int row=nt*16+4*g+j;
            fcbF[nt][j]=(row<POSE)? fcb[row] : 0.f;
        }
    }
    short8 wFC, wM; f32x4 fccC, mlpbF;
    if(lo<2){
        pk8 r;
        r.u[0]=f22bf(fccW[lo*16+4*g],   fccW[lo*16+4*g+1]);
        r.u[1]=f22bf(fccW[lo*16+4*g+2], fccW[lo*16+4*g+3]);
        r.u[2]=0u; r.u[3]=0u; wFC=r.s8;
    } else wFC=zero8();
    fccC=(g==0)? f32x4{fccb[0],fccb[1],0.f,0.f} : f32x4{0.f,0.f,0.f,0.f};
    {
        pk8 r;
        r.u[0]=f22bf(mlpW[lo*16+4*g],   mlpW[lo*16+4*g+1]);
        r.u[1]=f22bf(mlpW[lo*16+4*g+2], mlpW[lo*16+4*g+3]);
        r.u[2]=0u; r.u[3]=0u; wM=r.s8;
        mlpbF=*(const f32x4*)&mlpb[4*g];
    }

    // hc = mlp(h_enc) + mlpb
    unsigned hcp0,hcp1;
    {
        pk8 bh; bh.u[0]=hp0; bh.u[1]=hp1; bh.u[2]=0u; bh.u[3]=0u;
        f32x4 o=MF(wM,bh.s8,mlpbF);
        hcp0=f22bf(o[0],o[1]); hcp1=f22bf(o[2],o[3]);
    }
    f32x4 cC={0.f,0.f,0.f,0.f};
    unsigned pp=0u;

    auto dec_tail=[&](int s, const f32x4 (&aC)[4], const f32x4 (&aD)[4]){
        pw4v(aD,cS,hp0,hp1);
        pw4v(aC,cC,hcp0,hcp1);
        pk8 bhc; bhc.u[0]=hcp0; bhc.u[1]=hcp1; bhc.u[2]=0u; bhc.u[3]=0u;
        f32x4 zz=MF(wFC,bhc.s8,fccC);
        float z0=zz[0], z1=zz[1];
        float mx=fmaxf(z0,z1);
        float e0=EXP2(LOG2E*(z0-mx)), e1=EXP2(LOG2E*(z1-mx));
        float rs=RCP(e0+e1);
        float p0=e0*rs, p1=e1*rs;
        unsigned ppn=f22bf(p0,p1);
        if(g==0)
            ((float2*)out_cr)[(size_t)s*BATCH+pb+lo]=make_float2(p0,p1);
        pp=(unsigned)__shfl((int)ppn, lo, 64);
        pk8 bh; bh.u[0]=hp0; bh.u[1]=hp1; bh.u[2]=0u; bh.u[3]=0u;
        float* po = out_s + ((size_t)s*BATCH + pb + lo)*POSE;
        f32x4 o0=MF(wF[0],bh.s8,fcbF[0]);
        f32x4 o1=MF(wF[1],bh.s8,fcbF[1]);
        *(float2*)(po+4*g)     =make_float2(o0[0],o0[1]);
        *(float2*)(po+4*g+2)   =make_float2(o0[2],o0[3]);
        *(float2*)(po+16+4*g)  =make_float2(o1[0],o1[1]);
        *(float2*)(po+16+4*g+2)=make_float2(o1[2],o1[3]);
        f32x4 o2=MF(wF[2],bh.s8,fcbF[2]);
        if(g==0) *(float2*)(po+32)=make_float2(o2[0],o2[1]);
    };

    // ---- s=0 (peeled: original weights, pre-scaled on gather; inputs obs[31]) ----
    {
        f32x4 aC[4], aD[4];
#pragma unroll
        for(int gt=0;gt<4;++gt){
            float s=scGT(gt);
            int R=gt*16+lo;
            short8 a1=g8s(&cWih[R*34+8*g], s);
            pk8 a2;
            a2.u[0]=f22bf(cWhh[R*16+4*g]*s,   cWhh[R*16+4*g+1]*s);
            a2.u[1]=f22bf(cWhh[R*16+4*g+2]*s, cWhh[R*16+4*g+3]*s);
            a2.u[2]=(g==0)? f22bf(cWih[R*34+32]*s, cWih[R*34+33]*s) : 0u;
            a2.u[3]=0u;
            float4 ba=*(const float4*)&cbih[gt*16+4*g];
            float4 bb=*(const float4*)&cbhh[gt*16+4*g];
            f32x4 bc0={(ba.x+bb.x)*s,(ba.y+bb.y)*s,(ba.z+bb.z)*s,(ba.w+bb.w)*s};
            pk8 bhc; bhc.u[0]=hcp0; bhc.u[1]=hcp1; bhc.u[2]=(g==0)?ftQ:0u; bhc.u[3]=0u;
            f32x4 cx=MF(a1,fbQ,bc0);
            aC[gt]=MF(a2.s8,bhc.s8,cx);
            short8 d1=g8s(&dWih[R*34+8*g], s);
            pk8 d2;
            d2.u[0]=f22bf(dWhh[R*16+4*g]*s,   dWhh[R*16+4*g+1]*s);
            d2.u[1]=f22bf(dWhh[R*16+4*g+2]*s, dWhh[R*16+4*g+3]*s);
            d2.u[2]=(g==0)? f22bf(dWih[R*34+32]*s, dWih[R*34+33]*s) : 0u;
            d2.u[3]=0u;
            float4 da=*(const float4*)&dbih[gt*16+4*g];
            float4 db=*(const float4*)&dbhh[gt*16+4*g];
            f32x4 bd0={(da.x+db.x)*s,(da.y+db.y)*s,(da.z+db.z)*s,(da.w+db.w)*s};
            pk8 bhd; bhd.u[0]=hp0; bhd.u[1]=hp1; bhd.u[2]=(g==0)?ftQ:0u; bhd.u[3]=0u;
            f32x4 dx=MF(d1,fbQ,bd0);
            aD[gt]=MF(d2.s8,bhd.s8,dx);
        }
        dec_tail(0,aC,aD);
    }
    // ---- s=1..14: folded cells, lane-local, pure-register ----
    for(int s=1;s<PREDL;++s){
        pk8 bd; bd.u[0]=hp0; bd.u[1]=hp1; bd.u[2]=0u; bd.u[3]=0u;
        pk8 bc; bc.u[0]=hcp0; bc.u[1]=hcp1; bc.u[2]=(g==0)?pp:0u; bc.u[3]=0u;
        f32x4 aC[4], aD[4];
#pragma unroll
        for(int gt=0;gt<4;++gt) aD[gt]=MF(wDh[gt],bd.s8,biasD[gt]);
#pragma unroll
        for(int gt=0;gt<4;++gt) aC[gt]=MF(wCA[gt],bc.s8,biasC[gt]);
        dec_tail(s,aC,aD);
    }
}

extern "C" void kernel_launch(void* const* d_in, const int* in_sizes, int n_in,
                              void* d_out, int out_size, void* d_ws, size_t ws_size,
                              hipStream_t stream)
{
    const float* obs  = (const float*)d_in[0];
    const float* eWih = (const float*)d_in[1];
    const float* eWhh = (const float*)d_in[2];
    const float* ebih = (const float*)d_in[3];
    const float* ebhh = (const float*)d_in[4];
    const float* dWih = (const float*)d_in[5];
    const float* dWhh = (const float*)d_in[6];
    const float* dbih = (const float*)d_in[7];
    const float* dbhh = (const float*)d_in[8];
    const float* cWih = (const float*)d_in[9];
    const float* cWhh = (const float*)d_in[10];
    const float* cbih = (const float*)d_in[11];
    const float* cbhh = (const float*)d_in[12];
    const float* fcW  = (const float*)d_in[13];
    const float* fcb  = (const float*)d_in[14];
    const float* fccW = (const float*)d_in[15];
    const float* fccb = (const float*)d_in[16];
    const float* mlpW = (const float*)d_in[17];
    const float* mlpb = (const float*)d_in[18];
    const float* embW = (const float*)d_in[19];
    const float* embb = (const float*)d_in[20];

    float* out_s  = (float*)d_out;
    float* out_cr = out_s + (size_t)PREDL*BATCH*POSE;

    float* wsBD = (float*)d_ws;
    float* wsBC = wsBD + 64;
    unsigned short* wsDh = (unsigned short*)(wsBC+64);
    unsigned short* wsCh = wsDh + 1024;
    unsigned short* wsCp = wsCh + 1024;

    hipLaunchKernelGGL(lstm_prep, dim3(4), dim3(256), 0, stream,
                       dWih, dWhh, dbih, dbhh, cWih, cWhh, cbih, cbhh,
                       fcW, fcb, embW, embb, wsBD, wsBC, wsDh, wsCh, wsCp);
    hipLaunchKernelGGL(lstm_w9, dim3(BATCH/64), dim3(256), 0, stream,
                       obs, eWih, eWhh, ebih, ebhh, dWih, dWhh, dbih, dbhh,
                       cWih, cWhh, cbih, cbhh, fcW, fcb, fccW, fccb,
                       mlpW, mlpb, wsBD, wsBC, wsDh, wsCh, wsCp,
                       out_s, out_cr);
}

// Round 17
// 65.800 us; speedup vs baseline: 1.3765x; 1.3765x over previous
//
#include <hip/hip_runtime.h>
#include <cstddef>

#define SEQLEN 32
#define BATCH  32768
#define POSE   34
#define PREDL  15
#define LOG2E  1.4426950408889634f
#define K2E    2.8853901817779268f

typedef __attribute__((ext_vector_type(8))) short short8;
typedef __attribute__((ext_vector_type(4))) float f32x4;
typedef union { short8 s8; unsigned u[4]; } pk8;

#define MF(a,b,c) __builtin_amdgcn_mfma_f32_16x16x32_bf16(a,b,c,0,0,0)
#define EXP2(x)  __builtin_amdgcn_exp2f(x)
#define RCP(x)   __builtin_amdgcn_rcpf(x)

__device__ __forceinline__ unsigned short f2bf(float f){ __bf16 b=(__bf16)f; return __builtin_bit_cast(unsigned short,b); }
__device__ __forceinline__ unsigned f22bf(float lo,float hi){ return (unsigned)f2bf(lo) | ((unsigned)f2bf(hi)<<16); }
__device__ __forceinline__ short8 zero8(){ pk8 r; r.u[0]=0;r.u[1]=0;r.u[2]=0;r.u[3]=0; return r.s8; }
__device__ __forceinline__ float scGT(int gt){ return (gt==2)?K2E:LOG2E; }

__device__ __forceinline__ short8 g8s(const float* __restrict__ p, float s){
    pk8 r;
    r.u[0]=f22bf(p[0]*s,p[1]*s); r.u[1]=f22bf(p[2]*s,p[3]*s);
    r.u[2]=f22bf(p[4]*s,p[5]*s); r.u[3]=f22bf(p[6]*s,p[7]*s);
    return r.s8;
}

// async global->LDS, 4B per lane (per-lane global addr, wave-uniform LDS base)
__device__ __forceinline__ void gll4(const float* g, float* l){
    __builtin_amdgcn_global_load_lds(
        (const __attribute__((address_space(1))) unsigned*)g,
        (__attribute__((address_space(3))) unsigned*)l, 4, 0, 0);
}
// generic shared ptr -> 32-bit LDS byte offset
__device__ __forceinline__ unsigned ldsoff(const void* p){
    return (unsigned)(unsigned long long)(const __attribute__((address_space(3))) void*)p;
}
// raw ds_read_b64 (invisible to the compiler's waitcnt legalizer)
__device__ __forceinline__ float2 ds_rd64(unsigned addr){
    float2 r;
    asm volatile("ds_read_b64 %0, %1" : "=v"(r) : "v"(addr));
    return r;
}
#define WAIT_VM(N)  asm volatile("s_waitcnt vmcnt(" #N ")" ::: "memory")
#define WAIT_LGKM() asm volatile("s_waitcnt lgkmcnt(0)" ::: "memory")
#define SB0()       __builtin_amdgcn_sched_barrier(0)

// packed trans-reduced pointwise (identical numerics to R10)
__device__ __forceinline__ void pw4v(const f32x4 (&ac)[4], f32x4 &cs,
                                     unsigned &hp0, unsigned &hp1){
    f32x4 A,C,B,O;
#pragma unroll
    for(int j=0;j<4;++j){
        A[j]=EXP2(-ac[0][j]); C[j]=EXP2(-ac[1][j]);
        B[j]=EXP2( ac[2][j]); O[j]=EXP2(-ac[3][j]);
    }
    const f32x4 one={1.f,1.f,1.f,1.f};
    f32x4 u=one+A, w=one+C, v=B+one, Bm=B-one;
    f32x4 t1=u*v;
    f32x4 num=cs*t1+Bm*w;
    f32x4 den=t1*w;
    f32x4 rd_,E,rh;
#pragma unroll
    for(int j=0;j<4;++j) rd_[j]=RCP(den[j]);
    f32x4 cn=num*rd_;
    cs=cn;
#pragma unroll
    for(int j=0;j<4;++j) E[j]=EXP2(K2E*cn[j]);
    f32x4 hd=(one+O)*(E+one);
#pragma unroll
    for(int j=0;j<4;++j) rh[j]=RCP(hd[j]);
    f32x4 hv=(E-one)*rh;
    hp0=f22bf(hv[0],hv[1]); hp1=f22bf(hv[2],hv[3]);
}

// ---- prep: fold decoder/crossing weights, pre-scaled, into workspace ----
extern "C" __global__ void lstm_prep(
    const float* __restrict__ dWih, const float* __restrict__ dWhh,
    const float* __restrict__ dbih, const float* __restrict__ dbhh,
    const float* __restrict__ cWih, const float* __restrict__ cWhh,
    const float* __restrict__ cbih, const float* __restrict__ cbhh,
    const float* __restrict__ fcW,  const float* __restrict__ fcb,
    const float* __restrict__ embW, const float* __restrict__ embb,
    float* __restrict__ wsBD, float* __restrict__ wsBC,
    unsigned short* __restrict__ wsDh, unsigned short* __restrict__ wsCh,
    unsigned short* __restrict__ wsCp)
{
    int idx = blockIdx.x*256 + threadIdx.x;
    if(idx < 1024){
        int R=idx>>4, k=idx&15;
        float s=scGT(R>>4);
        float vD=dWhh[R*16+k];
        for(int p=0;p<34;++p) vD=fmaf(dWih[R*34+p],fcW[p*16+k],vD);
        wsDh[idx]=f2bf(vD*s);
        wsCh[idx]=f2bf(cWhh[R*16+k]*s);
    }
    if(idx < 128){
        int R=idx>>1, k=idx&1;
        float s=scGT(R>>4);
        float v=0.f;
        for(int p=0;p<34;++p) v=fmaf(cWih[R*34+p],embW[2*p+k],v);
        wsCp[idx]=f2bf(v*s);
    }
    if(idx < 64){
        int R=idx;
        float s=scGT(R>>4);
        float vD=dbih[R]+dbhh[R], vC=cbih[R]+cbhh[R];
        for(int p=0;p<34;++p){ vD=fmaf(dWih[R*34+p],fcb[p],vD); vC=fmaf(cWih[R*34+p],embb[p],vC); }
        wsBD[idx]=vD*s; wsBC[idx]=vC*s;
    }
}

extern "C" __global__ void __launch_bounds__(256,2) lstm_wA(
    const float* __restrict__ obs_s,
    const float* __restrict__ eWih, const float* __restrict__ eWhh,
    const float* __restrict__ ebih, const float* __restrict__ ebhh,
    const float* __restrict__ dWih, const float* __restrict__ dWhh,
    const float* __restrict__ dbih, const float* __restrict__ dbhh,
    const float* __restrict__ cWih, const float* __restrict__ cWhh,
    const float* __restrict__ cbih, const float* __restrict__ cbhh,
    const float* __restrict__ fcW,  const float* __restrict__ fcb,
    const float* __restrict__ fccW, const float* __restrict__ fccb,
    const float* __restrict__ mlpW, const float* __restrict__ mlpb,
    const float* __restrict__ wsBD, const float* __restrict__ wsBC,
    const unsigned short* __restrict__ wsDh, const unsigned short* __restrict__ wsCh,
    const unsigned short* __restrict__ wsCp,
    float* __restrict__ out_s, float* __restrict__ out_cr)
{
    // per-wave: 6 step-slots x 544 f32 (16 rows x 34, unpadded, row-major)
    __shared__ float xt6[4][6][544];    // 52,224 B

    const int tid=threadIdx.x;
    const int l=tid&63;
    const int wv=tid>>6;
    const int lo=l&15, g=l>>4;
    const int pb=blockIdx.x*64 + wv*16;

    // ---- prefetch: issue steps 0..5 immediately (latency overlaps weight setup) ----
    auto issue_step=[&](int t,int slot){
        const float* gb = obs_s + ((size_t)t*BATCH + pb)*34 + l;
        float* lb = &xt6[wv][slot][0];
#pragma unroll
        for(int it=0; it<8; ++it) gll4(gb + 64*it, lb + 64*it);
        if(l<32) gll4(gb + 512, lb + 512);
    };
#pragma unroll
    for(int t=0;t<6;++t) issue_step(t,t);

    // LDS byte-offset bases for this lane
    const unsigned xbW = ldsoff(&xt6[wv][0][0]);
    const unsigned xbG = xbW + (unsigned)(lo*136 + g*32);   // gate-frag base
    const unsigned xbT = xbW + (unsigned)(lo*136 + 128);    // tail base (x32,x33)

    // ---- encoder weights: A-frags, pre-scaled; bias as C-frag ----
    short8 wEx[4], wEhT[4]; f32x4 biasE[4];
#pragma unroll
    for(int gt=0;gt<4;++gt){
        float s=scGT(gt);
        int R=gt*16+lo;
        wEx[gt]=g8s(&eWih[R*34+8*g], s);
        pk8 r2;
        r2.u[0]=f22bf(eWhh[R*16+4*g]*s,   eWhh[R*16+4*g+1]*s);
        r2.u[1]=f22bf(eWhh[R*16+4*g+2]*s, eWhh[R*16+4*g+3]*s);
        r2.u[2]=(g==0)? f22bf(eWih[R*34+32]*s, eWih[R*34+33]*s) : 0u;
        r2.u[3]=0u;
        wEhT[gt]=r2.s8;
        float4 ba=*(const float4*)&ebih[gt*16+4*g];
        float4 bb=*(const float4*)&ebhh[gt*16+4*g];
        biasE[gt]=f32x4{(ba.x+bb.x)*s,(ba.y+bb.y)*s,(ba.z+bb.z)*s,(ba.w+bb.w)*s};
    }

    f32x4 cS={0.f,0.f,0.f,0.f};
    unsigned hp0=0u, hp1=0u;
    short8 fbQ=zero8(); unsigned ftQ=0u;

    // ---- encoder: 16 blocks of 2 steps; 6-step-deep async pipeline ----
#pragma unroll
    for(int Tb=0; Tb<16; ++Tb){
        const int T=2*Tb;
        // counted drain: guarantee steps T,T+1 landed (never full drain in steady state)
        if(T<=26)      WAIT_VM(36);
        else if(T==28) WAIT_VM(18);
        else           WAIT_VM(0);
        SB0();
        // raw LDS reads for steps T,T+1 (5x b64 each)
        const unsigned b0=xbG + (unsigned)((T  )%6)*2176u;
        const unsigned b1=xbG + (unsigned)((T+1)%6)*2176u;
        const unsigned t0=xbT + (unsigned)((T  )%6)*2176u;
        const unsigned t1=xbT + (unsigned)((T+1)%6)*2176u;
        float2 r0[4], r1[4], tl0, tl1;
#pragma unroll
        for(int q=0;q<4;++q){ r0[q]=ds_rd64(b0+8u*q); r1[q]=ds_rd64(b1+8u*q); }
        tl0=ds_rd64(t0); tl1=ds_rd64(t1);
        WAIT_LGKM();
        SB0();
        short8 bx[2]; unsigned tw2[2];
        {
            pk8 p0,p1;
#pragma unroll
            for(int q=0;q<4;++q){ p0.u[q]=f22bf(r0[q].x,r0[q].y); p1.u[q]=f22bf(r1[q].x,r1[q].y); }
            bx[0]=p0.s8; bx[1]=p1.s8;
            tw2[0]=f22bf(tl0.x,tl0.y); tw2[1]=f22bf(tl1.x,tl1.y);
        }
        SB0();
        // refill the two just-freed slots with steps T+6, T+7
        if(T+6<SEQLEN){ issue_step(T+6,(T+6)%6); issue_step(T+7,(T+7)%6); }
        // off-chain x-part MFMAs
        f32x4 cx[2][4];
#pragma unroll
        for(int s2=0;s2<2;++s2)
#pragma unroll
            for(int gt=0;gt<4;++gt)
                cx[s2][gt]=MF(wEx[gt],bx[s2],biasE[gt]);
        if(T==30){ fbQ=bx[1]; ftQ=tw2[1]; }
        // pure-register chain
#pragma unroll
        for(int s2=0;s2<2;++s2){
            pk8 bh; bh.u[0]=hp0; bh.u[1]=hp1; bh.u[2]=(g==0)?tw2[s2]:0u; bh.u[3]=0u;
            f32x4 acc[4];
#pragma unroll
            for(int gt=0;gt<4;++gt) acc[gt]=MF(wEhT[gt],bh.s8,cx[s2][gt]);
            pw4v(acc,cS,hp0,hp1);
        }
    }

    // ---- decoder weights -> VGPRs (folded, pre-scaled) ----
    short8 wDh[4], wCA[4]; f32x4 biasD[4], biasC[4];
#pragma unroll
    for(int gt=0;gt<4;++gt){
        int R=gt*16+lo;
        uint2 qd=*(const uint2*)&wsDh[R*16+4*g];
        pk8 rd; rd.u[0]=qd.x; rd.u[1]=qd.y; rd.u[2]=0u; rd.u[3]=0u;
        wDh[gt]=rd.s8;
        uint2 qc=*(const uint2*)&wsCh[R*16+4*g];
        pk8 rc; rc.u[0]=qc.x; rc.u[1]=qc.y;
        rc.u[2]=(g==0)? *(const unsigned*)&wsCp[R*2] : 0u; rc.u[3]=0u;
        wCA[gt]=rc.s8;
        biasD[gt]=*(const f32x4*)&wsBD[gt*16+4*g];
        biasC[gt]=*(const f32x4*)&wsBC[gt*16+4*g];
    }
    short8 wF[3]; f32x4 fcbF[3];
#pragma unroll
    for(int nt=0;nt<3;++nt){
        int np=nt*16+lo;
        if(np<POSE){
            pk8 r;
            r.u[0]=f22bf(fcW[np*16+4*g],   fcW[np*16+4*g+1]);
            r.u[1]=f22bf(fcW[np*16+4*g+2], fcW[np*16+4*g+3]);
            r.u[2]=0u; r.u[3]=0u;
            wF[nt]=r.s8;
        } else wF[nt]=zero8();
#pragma unroll
        for(int j=0;j<4;++j){
            int row=nt*16+4*g+j;
            fcbF[nt][j]=(row<POSE)? fcb[row] : 0.f;
        }
    }
    short8 wFC, wM; f32x4 fccC, mlpbF;
    if(lo<2){
        pk8 r;
        r.u[0]=f22bf(fccW[lo*16+4*g],   fccW[lo*16+4*g+1]);
        r.u[1]=f22bf(fccW[lo*16+4*g+2], fccW[lo*16+4*g+3]);
        r.u[2]=0u; r.u[3]=0u; wFC=r.s8;
    } else wFC=zero8();
    fccC=(g==0)? f32x4{fccb[0],fccb[1],0.f,0.f} : f32x4{0.f,0.f,0.f,0.f};
    {
        pk8 r;
        r.u[0]=f22bf(mlpW[lo*16+4*g],   mlpW[lo*16+4*g+1]);
        r.u[1]=f22bf(mlpW[lo*16+4*g+2], mlpW[lo*16+4*g+3]);
        r.u[2]=0u; r.u[3]=0u; wM=r.s8;
        mlpbF=*(const f32x4*)&mlpb[4*g];
    }

    // hc = mlp(h_enc) + mlpb
    unsigned hcp0,hcp1;
    {
        pk8 bh; bh.u[0]=hp0; bh.u[1]=hp1; bh.u[2]=0u; bh.u[3]=0u;
        f32x4 o=MF(wM,bh.s8,mlpbF);
        hcp0=f22bf(o[0],o[1]); hcp1=f22bf(o[2],o[3]);
    }
    f32x4 cC={0.f,0.f,0.f,0.f};
    unsigned pp=0u;

    auto dec_tail=[&](int s, const f32x4 (&aC)[4], const f32x4 (&aD)[4]){
        pw4v(aD,cS,hp0,hp1);
        pw4v(aC,cC,hcp0,hcp1);
        pk8 bhc; bhc.u[0]=hcp0; bhc.u[1]=hcp1; bhc.u[2]=0u; bhc.u[3]=0u;
        f32x4 zz=MF(wFC,bhc.s8,fccC);
        float z0=zz[0], z1=zz[1];
        float mx=fmaxf(z0,z1);
        float e0=EXP2(LOG2E*(z0-mx)), e1=EXP2(LOG2E*(z1-mx));
        float rs=RCP(e0+e1);
        float p0=e0*rs, p1=e1*rs;
        unsigned ppn=f22bf(p0,p1);
        if(g==0)
            ((float2*)out_cr)[(size_t)s*BATCH+pb+lo]=make_float2(p0,p1);
        pp=(unsigned)__shfl((int)ppn, lo, 64);
        pk8 bh; bh.u[0]=hp0; bh.u[1]=hp1; bh.u[2]=0u; bh.u[3]=0u;
        float* po = out_s + ((size_t)s*BATCH + pb + lo)*POSE;
        f32x4 o0=MF(wF[0],bh.s8,fcbF[0]);
        f32x4 o1=MF(wF[1],bh.s8,fcbF[1]);
        *(float2*)(po+4*g)     =make_float2(o0[0],o0[1]);
        *(float2*)(po+4*g+2)   =make_float2(o0[2],o0[3]);
        *(float2*)(po+16+4*g)  =make_float2(o1[0],o1[1]);
        *(float2*)(po+16+4*g+2)=make_float2(o1[2],o1[3]);
        f32x4 o2=MF(wF[2],bh.s8,fcbF[2]);
        if(g==0) *(float2*)(po+32)=make_float2(o2[0],o2[1]);
    };

    // ---- s=0 (peeled: original weights, pre-scaled on gather; inputs obs[31]) ----
    {
        f32x4 aC[4], aD[4];
#pragma unroll
        for(int gt=0;gt<4;++gt){
            float s=scGT(gt);
            int R=gt*16+lo;
            short8 a1=g8s(&cWih[R*34+8*g], s);
            pk8 a2;
            a2.u[0]=f22bf(cWhh[R*16+4*g]*s,   cWhh[R*16+4*g+1]*s);
            a2.u[1]=f22bf(cWhh[R*16+4*g+2]*s, cWhh[R*16+4*g+3]*s);
            a2.u[2]=(g==0)? f22bf(cWih[R*34+32]*s, cWih[R*34+33]*s) : 0u;
            a2.u[3]=0u;
            float4 ba=*(const float4*)&cbih[gt*16+4*g];
            float4 bb=*(const float4*)&cbhh[gt*16+4*g];
            f32x4 bc0={(ba.x+bb.x)*s,(ba.y+bb.y)*s,(ba.z+bb.z)*s,(ba.w+bb.w)*s};
            pk8 bhc; bhc.u[0]=hcp0; bhc.u[1]=hcp1; bhc.u[2]=(g==0)?ftQ:0u; bhc.u[3]=0u;
            f32x4 cx=MF(a1,fbQ,bc0);
            aC[gt]=MF(a2.s8,bhc.s8,cx);
            short8 d1=g8s(&dWih[R*34+8*g], s);
            pk8 d2;
            d2.u[0]=f22bf(dWhh[R*16+4*g]*s,   dWhh[R*16+4*g+1]*s);
            d2.u[1]=f22bf(dWhh[R*16+4*g+2]*s, dWhh[R*16+4*g+3]*s);
            d2.u[2]=(g==0)? f22bf(dWih[R*34+32]*s, dWih[R*34+33]*s) : 0u;
            d2.u[3]=0u;
            float4 da=*(const float4*)&dbih[gt*16+4*g];
            float4 db=*(const float4*)&dbhh[gt*16+4*g];
            f32x4 bd0={(da.x+db.x)*s,(da.y+db.y)*s,(da.z+db.z)*s,(da.w+db.w)*s};
            pk8 bhd; bhd.u[0]=hp0; bhd.u[1]=hp1; bhd.u[2]=(g==0)?ftQ:0u; bhd.u[3]=0u;
            f32x4 dx=MF(d1,fbQ,bd0);
            aD[gt]=MF(d2.s8,bhd.s8,dx);
        }
        dec_tail(0,aC,aD);
    }
    // ---- s=1..14: folded cells, lane-local, pure-register ----
    for(int s=1;s<PREDL;++s){
        pk8 bd; bd.u[0]=hp0; bd.u[1]=hp1; bd.u[2]=0u; bd.u[3]=0u;
        pk8 bc; bc.u[0]=hcp0; bc.u[1]=hcp1; bc.u[2]=(g==0)?pp:0u; bc.u[3]=0u;
        f32x4 aC[4], aD[4];
#pragma unroll
        for(int gt=0;gt<4;++gt) aD[gt]=MF(wDh[gt],bd.s8,biasD[gt]);
#pragma unroll
        for(int gt=0;gt<4;++gt) aC[gt]=MF(wCA[gt],bc.s8,biasC[gt]);
        dec_tail(s,aC,aD);
    }
}

extern "C" void kernel_launch(void* const* d_in, const int* in_sizes, int n_in,
                              void* d_out, int out_size, void* d_ws, size_t ws_size,
                              hipStream_t stream)
{
    const float* obs  = (const float*)d_in[0];
    const float* eWih = (const float*)d_in[1];
    const float* eWhh = (const float*)d_in[2];
    const float* ebih = (const float*)d_in[3];
    const float* ebhh = (const float*)d_in[4];
    const float* dWih = (const float*)d_in[5];
    const float* dWhh = (const float*)d_in[6];
    const float* dbih = (const float*)d_in[7];
    const float* dbhh = (const float*)d_in[8];
    const float* cWih = (const float*)d_in[9];
    const float* cWhh = (const float*)d_in[10];
    const float* cbih = (const float*)d_in[11];
    const float* cbhh = (const float*)d_in[12];
    const float* fcW  = (const float*)d_in[13];
    const float* fcb  = (const float*)d_in[14];
    const float* fccW = (const float*)d_in[15];
    const float* fccb = (const float*)d_in[16];
    const float* mlpW = (const float*)d_in[17];
    const float* mlpb = (const float*)d_in[18];
    const float* embW = (const float*)d_in[19];
    const float* embb = (const float*)d_in[20];

    float* out_s  = (float*)d_out;
    float* out_cr = out_s + (size_t)PREDL*BATCH*POSE;

    float* wsBD = (float*)d_ws;
    float* wsBC = wsBD + 64;
    unsigned short* wsDh = (unsigned short*)(wsBC+64);
    unsigned short* wsCh = wsDh + 1024;
    unsigned short* wsCp = wsCh + 1024;

    hipLaunchKernelGGL(lstm_prep, dim3(4), dim3(256), 0, stream,
                       dWih, dWhh, dbih, dbhh, cWih, cWhh, cbih, cbhh,
                       fcW, fcb, embW, embb, wsBD, wsBC, wsDh, wsCh, wsCp);
    hipLaunchKernelGGL(lstm_wA, dim3(BATCH/64), dim3(256), 0, stream,
                       obs, eWih, eWhh, ebih, ebhh, dWih, dWhh, dbih, dbhh,
                       cWih, cWhh, cbih, cbhh, fcW, fcb, fccW, fccb,
                       mlpW, mlpb, wsBD, wsBC, wsDh, wsCh, wsCp,
                       out_s, out_cr);
}